// Round 1
// baseline (1158.900 us; speedup 1.0000x reference)
//
#include <hip/hip_runtime.h>
#include <hip/hip_bf16.h>

// Attention_89335319756981 — MI355X bf16-MFMA implementation, round 1.
// B=8, N=2880 (hw=576 + T=4 frames of 576), C=768, H=12, hd=64, TOPK=32.
//
// Pipeline:
//  1) cvt x, qkv_w, proj_w -> bf16 (ws)
//  2) QKV GEMM (bf16 MFMA, NT): scatter q(*0.125), k, v, vT.  k/v live in d_out.
//  3) fused attn per (b,h,8 q-rows): scores MFMA -> LDS, exact top-32 per frame
//     (ballot binary-search on u16 keys), softmax (no max-sub; scores are small),
//     dense PV MFMA over qa + sparse 128-term gather, -> attn_out bf16
//  4) proj GEMM (+bias) -> d_out rows [0,576) per batch
//  5) passthrough copy x[:,576:] -> d_out (exact f32)

using s16x8 = __attribute__((ext_vector_type(8))) short;
using f32x4 = __attribute__((ext_vector_type(4))) float;
typedef unsigned short u16;

#define MFMA_B16(A,B,C) __builtin_amdgcn_mfma_f32_16x16x32_bf16(A,B,C,0,0,0)

__device__ __forceinline__ u16 f2bf(float f) {
  unsigned u = __float_as_uint(f);
  u += 0x7FFFu + ((u >> 16) & 1u);          // RNE, no NaN inputs here
  return (u16)(u >> 16);
}
__device__ __forceinline__ float bf2f(u16 h) {
  return __uint_as_float(((unsigned)h) << 16);
}
__device__ __forceinline__ int lanes_below(unsigned long long m) {
  return __builtin_amdgcn_mbcnt_hi((unsigned)(m >> 32),
         __builtin_amdgcn_mbcnt_lo((unsigned)m, 0));
}

// ---------------- f32 -> bf16 convert (4 elems/thread) ----------------
__global__ __launch_bounds__(256) void cvt_kernel(const float* __restrict__ src,
                                                  u16* __restrict__ dst, int n4) {
  int i = blockIdx.x * blockDim.x + threadIdx.x;
  if (i >= n4) return;
  float4 v = ((const float4*)src)[i];
  unsigned lo = (unsigned)f2bf(v.x) | ((unsigned)f2bf(v.y) << 16);
  unsigned hi = (unsigned)f2bf(v.z) | ((unsigned)f2bf(v.w) << 16);
  uint2 o; o.x = lo; o.y = hi;
  ((uint2*)dst)[i] = o;
}

// ---------------- passthrough copy: out[:,576:,:] = x[:,576:,:] ----------------
__global__ __launch_bounds__(256) void copy_tail_kernel(const float* __restrict__ x,
                                                        float* __restrict__ out) {
  int i = blockIdx.x * blockDim.x + threadIdx.x;   // 0 .. 3538943 (float4 units)
  int b = i / 442368;                              // 2304*768/4 per batch
  int off = i - b * 442368;
  size_t e = (size_t)b * 552960 + 110592 + off;    // (b*2880+576)*768/4 + off
  ((float4*)out)[e] = ((const float4*)x)[e];
}

// ---------------- NT GEMM: C[m][n] = sum_k A[m][k]*Bw[n][k], bf16 MFMA ----------------
// 64x64 block tile, 4 waves of 32x32, K-step 64. LDS padded stride 144B.
// MODE 0: QKV epilogue (scatter q/k/v/vT). MODE 1: proj epilogue (f32 + bias -> out).
template<int MODE>
__global__ __launch_bounds__(256) void gemm_nt(
    const u16* __restrict__ A, const u16* __restrict__ Bw,
    const float* __restrict__ bias,
    u16* __restrict__ qbuf, u16* __restrict__ kbuf,
    u16* __restrict__ vbuf, u16* __restrict__ vtb,
    float* __restrict__ fout)
{
  constexpr int LDT = 72;   // u16 per LDS row (144 B) — +16B pad kills bank conflicts
  __shared__ __align__(16) u16 sA[64 * LDT];
  __shared__ __align__(16) u16 sB[64 * LDT];
  const int n0 = blockIdx.x * 64;
  const int m0 = blockIdx.y * 64;
  if (MODE == 0) {
    // q columns (n<768) only need rows r<576 of each batch (m-tile%45 < 9)
    if (n0 < 768 && (blockIdx.y % 45) >= 9) return;
  }
  const int tid = threadIdx.x;
  const int w = tid >> 6, lane = tid & 63;
  const int srow = tid >> 2, scb = tid & 3;
  const int mh = (w >> 1) * 32, nh = (w & 1) * 32;
  f32x4 z = {0.f, 0.f, 0.f, 0.f};
  f32x4 acc[2][2] = {{z, z}, {z, z}};

  for (int k0 = 0; k0 < 768; k0 += 64) {
    __syncthreads();
    #pragma unroll
    for (int c = scb; c < 8; c += 4) {
      *(int4*)&sA[srow * LDT + c * 8] =
          *(const int4*)&A[(size_t)(m0 + srow) * 768 + k0 + c * 8];
      *(int4*)&sB[srow * LDT + c * 8] =
          *(const int4*)&Bw[(size_t)(n0 + srow) * 768 + k0 + c * 8];
    }
    __syncthreads();
    #pragma unroll
    for (int kk = 0; kk < 2; ++kk) {
      const int ko = kk * 32 + (lane >> 4) * 8;
      s16x8 a0 = *(const s16x8*)&sA[(mh +      (lane & 15)) * LDT + ko];
      s16x8 a1 = *(const s16x8*)&sA[(mh + 16 + (lane & 15)) * LDT + ko];
      s16x8 b0 = *(const s16x8*)&sB[(nh +      (lane & 15)) * LDT + ko];
      s16x8 b1 = *(const s16x8*)&sB[(nh + 16 + (lane & 15)) * LDT + ko];
      acc[0][0] = MFMA_B16(a0, b0, acc[0][0]);
      acc[0][1] = MFMA_B16(a0, b1, acc[0][1]);
      acc[1][0] = MFMA_B16(a1, b0, acc[1][0]);
      acc[1][1] = MFMA_B16(a1, b1, acc[1][1]);
    }
  }

  if (MODE == 0) {
    const int which = n0 / 768;           // uniform per block
    const int h = (n0 % 768) >> 6;        // head, uniform (64-wide tiles align)
    #pragma unroll
    for (int mi = 0; mi < 2; ++mi)
      #pragma unroll
      for (int ni = 0; ni < 2; ++ni)
        #pragma unroll
        for (int r = 0; r < 4; ++r) {
          const int gm = m0 + mh + mi * 16 + (lane >> 4) * 4 + r;
          const int d  = nh + ni * 16 + (lane & 15);
          const int b  = gm / 2880;
          const int rr = gm - b * 2880;
          const float c = acc[mi][ni][r];
          if (which == 0) {
            if (rr < 576)
              qbuf[((size_t)(b * 12 + h) * 576 + rr) * 64 + d] = f2bf(c * 0.125f);
          } else if (which == 1) {
            kbuf[((size_t)(b * 12 + h) * 2880 + rr) * 64 + d] = f2bf(c);
          } else {
            const u16 bv = f2bf(c);
            vbuf[((size_t)(b * 12 + h) * 2880 + rr) * 64 + d] = bv;
            vtb[((size_t)((b * 12 + h) * 64 + d)) * 2880 + rr] = bv;
          }
        }
  } else {
    #pragma unroll
    for (int mi = 0; mi < 2; ++mi)
      #pragma unroll
      for (int ni = 0; ni < 2; ++ni)
        #pragma unroll
        for (int r = 0; r < 4; ++r) {
          const int gm = m0 + mh + mi * 16 + (lane >> 4) * 4 + r;
          const int gn = n0 + nh + ni * 16 + (lane & 15);
          const int b = gm / 576;
          const int q = gm - b * 576;
          fout[((size_t)b * 2880 + q) * 768 + gn] = acc[mi][ni][r] + bias[gn];
        }
  }
}

// ---------------- fused attention: scores -> top-32/frame -> softmax -> PV ----------------
// block = (b, h, 8 q-rows), 256 threads (4 waves).
__global__ __launch_bounds__(256) void attn_kernel(
    const u16* __restrict__ qbuf, const u16* __restrict__ kbuf,
    const u16* __restrict__ vbuf, const u16* __restrict__ vtb,
    u16* __restrict__ aout)
{
  constexpr int SST = 2888;               // u16 stride per score row (5776 B = 361*16)
  __shared__ __align__(16) u16 s_sc[8 * SST];     // 46.2 KB scores / later P
  __shared__ float s_selp[8][128];                // exp(score) of selected
  __shared__ u16   s_seli[8][128];                // key index (global, 576..2879)
  __shared__ float s_spacc[8][64];                // sparse PV partial
  __shared__ float s_denom[8];

  const int qt = blockIdx.x, h = blockIdx.y, b = blockIdx.z;
  const int bh = b * 12 + h;
  const int tid = threadIdx.x, w = tid >> 6, lane = tid & 63;
  const int qb0 = qt * 8;
  const int ko = (lane >> 4) * 8;

  // Q fragments: rows lane&7 (rows 8..15 of the MFMA tile are duplicates, ignored)
  const u16* qp = qbuf + ((size_t)bh * 576 + qb0) * 64;
  const int qrow = lane & 7;
  s16x8 qf0 = *(const s16x8*)&qp[qrow * 64 + ko];
  s16x8 qf1 = *(const s16x8*)&qp[qrow * 64 + 32 + ko];

  // ---- scores: wave w covers keys [w*720, (w+1)*720), B-frags straight from global ----
  const u16* kp = kbuf + (size_t)bh * 2880 * 64;
  for (int t = 0; t < 45; ++t) {
    const int key0 = w * 720 + t * 16;
    const u16* kr = kp + (size_t)(key0 + (lane & 15)) * 64 + ko;
    s16x8 kf0 = *(const s16x8*)&kr[0];
    s16x8 kf1 = *(const s16x8*)&kr[32];
    f32x4 acc = {0.f, 0.f, 0.f, 0.f};
    acc = MFMA_B16(qf0, kf0, acc);
    acc = MFMA_B16(qf1, kf1, acc);
    if ((lane >> 4) < 2) {
      const int rg = lane >> 4;
      #pragma unroll
      for (int r = 0; r < 4; ++r)
        s_sc[(rg * 4 + r) * SST + key0 + (lane & 15)] = f2bf(acc[r]);
    }
  }
  __syncthreads();

  // ---- exact top-32 per (q-row, frame): one wave per task, 8 tasks/wave ----
  for (int it = 0; it < 8; ++it) {
    const int task = w * 8 + it;
    const int q = task >> 2, tf = task & 3;
    const int base = 576 + tf * 576;
    unsigned key[9];
    #pragma unroll
    for (int j = 0; j < 9; ++j) {
      unsigned raw = s_sc[q * SST + base + lane + 64 * j];
      key[j] = (raw & 0x8000u) ? (raw ^ 0xFFFFu) : (raw | 0x8000u);  // monotonic u16
    }
    unsigned prefix = 0;
    for (int bit = 15; bit >= 0; --bit) {
      const unsigned cand = prefix | (1u << bit);
      int cnt = 0;
      #pragma unroll
      for (int j = 0; j < 9; ++j)
        cnt += __popcll(__ballot(key[j] >= cand));
      if (cnt >= 32) prefix = cand;
      if (cnt == 32) break;                 // exactly the top-32 set
    }
    unsigned long long gtm[9], eqm[9];
    int cnt_gt = 0;
    #pragma unroll
    for (int j = 0; j < 9; ++j) {
      gtm[j] = __ballot(key[j] > prefix);
      eqm[j] = __ballot(key[j] == prefix);
      cnt_gt += __popcll(gtm[j]);
    }
    int run_gt = 0, run_eq = cnt_gt;
    #pragma unroll
    for (int j = 0; j < 9; ++j) {
      int slot = -1;
      if (key[j] > prefix) slot = run_gt + lanes_below(gtm[j]);
      else if (key[j] == prefix) {
        const int s2 = run_eq + lanes_below(eqm[j]);   // ties: lowest index first
        if (s2 < 32) slot = s2;
      }
      if (slot >= 0) {
        const unsigned kk = key[j];
        const u16 raw = (kk & 0x8000u) ? (u16)(kk ^ 0x8000u) : (u16)(kk ^ 0xFFFFu);
        s_selp[q][tf * 32 + slot] = __expf(bf2f(raw));
        s_seli[q][tf * 32 + slot] = (u16)(base + lane + 64 * j);
      }
      run_gt += __popcll(gtm[j]);
      run_eq += __popcll(eqm[j]);
    }
  }
  __syncthreads();

  // ---- per-row: denom, P-fill over qa (in place), sparse PV gather ----
  #pragma unroll
  for (int ri = 0; ri < 2; ++ri) {
    const int q = w * 2 + ri;
    float part = 0.f;
    #pragma unroll
    for (int i = 0; i < 9; ++i) {
      const int col = lane + 64 * i;
      const float p = __expf(bf2f(s_sc[q * SST + col]));
      s_sc[q * SST + col] = f2bf(p);
      part += p;
    }
    part += s_selp[q][lane] + s_selp[q][lane + 64];
    #pragma unroll
    for (int off = 1; off < 64; off <<= 1)
      part += __shfl_xor(part, off);
    if (lane == 0) s_denom[q] = part;
    // sparse PV: lane = dim d, 128 selected keys
    float sacc = 0.f;
    const u16* vp = vbuf + (size_t)bh * 2880 * 64 + lane;
    #pragma unroll 4
    for (int i = 0; i < 128; ++i) {
      const float p = s_selp[q][i];
      const int keyi = s_seli[q][i];
      sacc += p * bf2f(vp[(size_t)keyi * 64]);
    }
    s_spacc[q][lane] = sacc;
  }
  __syncthreads();

  // ---- dense PV over qa region via MFMA (B-frags from vT global) + epilogue ----
  f32x4 acc = {0.f, 0.f, 0.f, 0.f};
  const int d = w * 16 + (lane & 15);
  const u16* vt = vtb + ((size_t)(bh * 64 + d)) * 2880 + ko;
  #pragma unroll
  for (int k0 = 0; k0 < 576; k0 += 32) {
    s16x8 pa = *(const s16x8*)&s_sc[(lane & 7) * SST + k0 + ko];
    s16x8 vf = *(const s16x8*)&vt[k0];
    acc = MFMA_B16(pa, vf, acc);
  }
  if ((lane >> 4) < 2) {
    const int rg = lane >> 4;
    #pragma unroll
    for (int r = 0; r < 4; ++r) {
      const int row = rg * 4 + r;
      const float v = (acc[r] + s_spacc[row][d]) / s_denom[row];
      aout[((size_t)(b * 576 + qb0 + row)) * 768 + h * 64 + d] = f2bf(v);
    }
  }
}

// ---------------- host launcher ----------------
extern "C" void kernel_launch(void* const* d_in, const int* in_sizes, int n_in,
                              void* d_out, int out_size, void* d_ws, size_t ws_size,
                              hipStream_t stream)
{
  const float* x      = (const float*)d_in[0];
  const float* qkv_w  = (const float*)d_in[1];
  const float* proj_w = (const float*)d_in[2];
  const float* proj_b = (const float*)d_in[3];
  float* out = (float*)d_out;

  char* ws = (char*)d_ws;
  size_t off = 0;
  auto alloc = [&](size_t bytes) -> void* {
    void* p = ws + off;
    off += (bytes + 255) & ~(size_t)255;
    return p;
  };
  u16* xb   = (u16*)alloc((size_t)23040 * 768 * 2);   // x bf16
  u16* wqb  = (u16*)alloc((size_t)2304 * 768 * 2);    // qkv_w bf16
  u16* wpb  = (u16*)alloc((size_t)768 * 768 * 2);     // proj_w bf16
  u16* qbuf = (u16*)alloc((size_t)96 * 576 * 64 * 2); // q (pre-scaled 1/8)
  u16* vtb  = (u16*)alloc((size_t)96 * 64 * 2880 * 2);// v transposed per (b,h)
  u16* aout = (u16*)alloc((size_t)4608 * 768 * 2);    // attention output (B*hw, C)
  // k/v (70.8 MB total) live inside d_out during the early phases; proj +
  // passthrough overwrite d_out only after attn has consumed them.
  u16* kbuf = (u16*)d_out;
  u16* vbuf = kbuf + (size_t)96 * 2880 * 64;

  cvt_kernel<<<17280, 256, 0, stream>>>(x, xb, 17694720 / 4);
  cvt_kernel<<<1728, 256, 0, stream>>>(qkv_w, wqb, 1769472 / 4);
  cvt_kernel<<<576, 256, 0, stream>>>(proj_w, wpb, 589824 / 4);
  gemm_nt<0><<<dim3(36, 360), 256, 0, stream>>>(xb, wqb, nullptr,
                                                qbuf, kbuf, vbuf, vtb, nullptr);
  attn_kernel<<<dim3(72, 12, 8), 256, 0, stream>>>(qbuf, kbuf, vbuf, vtb, aout);
  gemm_nt<1><<<dim3(12, 72), 256, 0, stream>>>(aout, wpb, proj_b,
                                               nullptr, nullptr, nullptr, nullptr, out);
  copy_tail_kernel<<<13824, 256, 0, stream>>>(x, out);
}

// Round 2
// 751.507 us; speedup vs baseline: 1.5421x; 1.5421x over previous
//
#include <hip/hip_runtime.h>
#include <hip/hip_bf16.h>

// Attention_89335319756981 — MI355X bf16-MFMA implementation, round 2.
// B=8, N=2880 (hw=576 + T=4 frames of 576), C=768, H=12, hd=64, TOPK=32.
//
// Round-2 change: attn restructured to 32 q-rows/block, chunked over 5 key
// chunks of 576, fused topk+gather per wave, PV accum in registers+LDS.

using s16x8 = __attribute__((ext_vector_type(8))) short;
using f32x4 = __attribute__((ext_vector_type(4))) float;
typedef unsigned short u16;

#define MFMA_B16(A,B,C) __builtin_amdgcn_mfma_f32_16x16x32_bf16(A,B,C,0,0,0)

__device__ __forceinline__ u16 f2bf(float f) {
  unsigned u = __float_as_uint(f);
  u += 0x7FFFu + ((u >> 16) & 1u);          // RNE, no NaN inputs here
  return (u16)(u >> 16);
}
__device__ __forceinline__ float bf2f(u16 h) {
  return __uint_as_float(((unsigned)h) << 16);
}
__device__ __forceinline__ int lanes_below(unsigned long long m) {
  return __builtin_amdgcn_mbcnt_hi((unsigned)(m >> 32),
         __builtin_amdgcn_mbcnt_lo((unsigned)m, 0));
}

// ---------------- f32 -> bf16 convert (4 elems/thread) ----------------
__global__ __launch_bounds__(256) void cvt_kernel(const float* __restrict__ src,
                                                  u16* __restrict__ dst, int n4) {
  int i = blockIdx.x * blockDim.x + threadIdx.x;
  if (i >= n4) return;
  float4 v = ((const float4*)src)[i];
  unsigned lo = (unsigned)f2bf(v.x) | ((unsigned)f2bf(v.y) << 16);
  unsigned hi = (unsigned)f2bf(v.z) | ((unsigned)f2bf(v.w) << 16);
  uint2 o; o.x = lo; o.y = hi;
  ((uint2*)dst)[i] = o;
}

// ---------------- passthrough copy: out[:,576:,:] = x[:,576:,:] ----------------
__global__ __launch_bounds__(256) void copy_tail_kernel(const float* __restrict__ x,
                                                        float* __restrict__ out) {
  int i = blockIdx.x * blockDim.x + threadIdx.x;   // float4 units
  int b = i / 442368;                              // 2304*768/4 per batch
  int off = i - b * 442368;
  size_t e = (size_t)b * 552960 + 110592 + off;    // (b*2880+576)*768/4 + off
  ((float4*)out)[e] = ((const float4*)x)[e];
}

// ---------------- NT GEMM: C[m][n] = sum_k A[m][k]*Bw[n][k], bf16 MFMA ----------------
// 64x64 block tile, 4 waves of 32x32, K-step 64. LDS padded stride 144B.
// MODE 0: QKV epilogue (scatter q/k/v/vT-qa). MODE 1: proj epilogue (f32 + bias -> out).
template<int MODE>
__global__ __launch_bounds__(256) void gemm_nt(
    const u16* __restrict__ A, const u16* __restrict__ Bw,
    const float* __restrict__ bias,
    u16* __restrict__ qbuf, u16* __restrict__ kbuf,
    u16* __restrict__ vbuf, u16* __restrict__ vtb,
    float* __restrict__ fout)
{
  constexpr int LDT = 72;   // u16 per LDS row (144 B)
  __shared__ __align__(16) u16 sA[64 * LDT];
  __shared__ __align__(16) u16 sB[64 * LDT];
  const int n0 = blockIdx.x * 64;
  const int m0 = blockIdx.y * 64;
  if (MODE == 0) {
    // q columns (n<768) only need rows r<576 of each batch (m-tile%45 < 9)
    if (n0 < 768 && (blockIdx.y % 45) >= 9) return;
  }
  const int tid = threadIdx.x;
  const int w = tid >> 6, lane = tid & 63;
  const int srow = tid >> 2, scb = tid & 3;
  const int mh = (w >> 1) * 32, nh = (w & 1) * 32;
  f32x4 z = {0.f, 0.f, 0.f, 0.f};
  f32x4 acc[2][2] = {{z, z}, {z, z}};

  for (int k0 = 0; k0 < 768; k0 += 64) {
    __syncthreads();
    #pragma unroll
    for (int c = scb; c < 8; c += 4) {
      *(int4*)&sA[srow * LDT + c * 8] =
          *(const int4*)&A[(size_t)(m0 + srow) * 768 + k0 + c * 8];
      *(int4*)&sB[srow * LDT + c * 8] =
          *(const int4*)&Bw[(size_t)(n0 + srow) * 768 + k0 + c * 8];
    }
    __syncthreads();
    #pragma unroll
    for (int kk = 0; kk < 2; ++kk) {
      const int ko = kk * 32 + (lane >> 4) * 8;
      s16x8 a0 = *(const s16x8*)&sA[(mh +      (lane & 15)) * LDT + ko];
      s16x8 a1 = *(const s16x8*)&sA[(mh + 16 + (lane & 15)) * LDT + ko];
      s16x8 b0 = *(const s16x8*)&sB[(nh +      (lane & 15)) * LDT + ko];
      s16x8 b1 = *(const s16x8*)&sB[(nh + 16 + (lane & 15)) * LDT + ko];
      acc[0][0] = MFMA_B16(a0, b0, acc[0][0]);
      acc[0][1] = MFMA_B16(a0, b1, acc[0][1]);
      acc[1][0] = MFMA_B16(a1, b0, acc[1][0]);
      acc[1][1] = MFMA_B16(a1, b1, acc[1][1]);
    }
  }

  if (MODE == 0) {
    const int which = n0 / 768;           // uniform per block
    const int h = (n0 % 768) >> 6;        // head, uniform
    #pragma unroll
    for (int mi = 0; mi < 2; ++mi)
      #pragma unroll
      for (int ni = 0; ni < 2; ++ni)
        #pragma unroll
        for (int r = 0; r < 4; ++r) {
          const int gm = m0 + mh + mi * 16 + (lane >> 4) * 4 + r;
          const int d  = nh + ni * 16 + (lane & 15);
          const int b  = gm / 2880;
          const int rr = gm - b * 2880;
          const float c = acc[mi][ni][r];
          if (which == 0) {
            if (rr < 576)
              qbuf[((size_t)(b * 12 + h) * 576 + rr) * 64 + d] = f2bf(c * 0.125f);
          } else if (which == 1) {
            kbuf[((size_t)(b * 12 + h) * 2880 + rr) * 64 + d] = f2bf(c);
          } else {
            const u16 bv = f2bf(c);
            vbuf[((size_t)(b * 12 + h) * 2880 + rr) * 64 + d] = bv;
            if (rr < 576)  // vT only needed for the dense (qa) PV region
              vtb[((size_t)((b * 12 + h) * 64 + d)) * 576 + rr] = bv;
          }
        }
  } else {
    #pragma unroll
    for (int mi = 0; mi < 2; ++mi)
      #pragma unroll
      for (int ni = 0; ni < 2; ++ni)
        #pragma unroll
        for (int r = 0; r < 4; ++r) {
          const int gm = m0 + mh + mi * 16 + (lane >> 4) * 4 + r;
          const int gn = n0 + nh + ni * 16 + (lane & 15);
          const int b = gm / 576;
          const int q = gm - b * 576;
          fout[((size_t)b * 2880 + q) * 768 + gn] = acc[mi][ni][r] + bias[gn];
        }
  }
}

// ---------------- fused attention, round 2 ----------------
// block = (b, h, 32 q-rows), 256 threads (4 waves). 5 key-chunks of 576.
// Chunk 0 (qa): scores->exp->LDS P; dense PV MFMA into registers; denom pass.
// Chunks 1-4 (frames): scores->LDS; per-wave top-32 (ballot binary search) +
// denom add + coalesced sparse V gather into LDS accumulator s_O.
__global__ __launch_bounds__(256) void attn_kernel(
    const u16* __restrict__ qbuf, const u16* __restrict__ kbuf,
    const u16* __restrict__ vbuf, const u16* __restrict__ vtb,
    u16* __restrict__ aout)
{
  constexpr int PST = 584;                       // u16 stride (1168 B)
  __shared__ __align__(16) u16 s_p[32 * PST];    // 37.4 KB scores / P
  __shared__ float s_selp[32][32];               // exp(score) of selected
  __shared__ u16   s_seli[32][32];               // global key idx (576..2879)
  __shared__ float s_O[32][64];                  // sparse PV accumulator
  __shared__ float s_denom[32];

  const int qt = blockIdx.x, h = blockIdx.y, b = blockIdx.z;
  const int bh = b * 12 + h;
  const int q0 = qt * 32;
  const int tid = threadIdx.x, w = tid >> 6, lane = tid & 63;
  const int l15 = lane & 15, rg = lane >> 4;
  const int ko = rg * 8;

  #pragma unroll
  for (int i = 0; i < 8; ++i) ((float*)s_O)[tid + 256 * i] = 0.f;

  // Q A-fragments for the block's 32 rows (2 subtiles x 2 K-halves)
  const u16* qp = qbuf + ((size_t)bh * 576 + q0) * 64;
  s16x8 aQ[2][2];
  #pragma unroll
  for (int qa = 0; qa < 2; ++qa)
    #pragma unroll
    for (int kc = 0; kc < 2; ++kc)
      aQ[qa][kc] = *(const s16x8*)&qp[(qa * 16 + l15) * 64 + kc * 32 + ko];

  const u16* kp = kbuf + (size_t)bh * 2880 * 64;
  f32x4 zz = {0.f, 0.f, 0.f, 0.f};
  f32x4 accO[2] = {zz, zz};

  for (int c = 0; c < 5; ++c) {
    // ---- scores: wave w covers chunk-local keys [w*144, w*144+144) ----
    #pragma unroll 3
    for (int t = 0; t < 9; ++t) {
      const int wk = w * 144 + t * 16;
      const u16* kr = kp + (size_t)(c * 576 + wk + l15) * 64 + ko;
      s16x8 kf0 = *(const s16x8*)&kr[0];
      s16x8 kf1 = *(const s16x8*)&kr[32];
      f32x4 a0 = zz, a1 = zz;
      a0 = MFMA_B16(aQ[0][0], kf0, a0);
      a0 = MFMA_B16(aQ[0][1], kf1, a0);
      a1 = MFMA_B16(aQ[1][0], kf0, a1);
      a1 = MFMA_B16(aQ[1][1], kf1, a1);
      if (c == 0) {
        #pragma unroll
        for (int r = 0; r < 4; ++r) {
          s_p[(rg * 4 + r) * PST + wk + l15]        = f2bf(__expf(a0[r]));
          s_p[(16 + rg * 4 + r) * PST + wk + l15]   = f2bf(__expf(a1[r]));
        }
      } else {
        #pragma unroll
        for (int r = 0; r < 4; ++r) {
          s_p[(rg * 4 + r) * PST + wk + l15]        = f2bf(a0[r]);
          s_p[(16 + rg * 4 + r) * PST + wk + l15]   = f2bf(a1[r]);
        }
      }
    }
    __syncthreads();

    if (c == 0) {
      // ---- dense PV over qa: wave w owns output cols d = w*16..w*16+15 ----
      const u16* vt = vtb + ((size_t)bh * 64 + w * 16 + l15) * 576;
      #pragma unroll 3
      for (int k0 = 0; k0 < 576; k0 += 32) {
        s16x8 vf = *(const s16x8*)&vt[k0 + ko];
        #pragma unroll
        for (int qa = 0; qa < 2; ++qa) {
          s16x8 pa = *(const s16x8*)&s_p[(qa * 16 + l15) * PST + k0 + ko];
          accO[qa] = MFMA_B16(pa, vf, accO[qa]);
        }
      }
      // ---- denom over qa: wave w owns rows w*8..w*8+7 ----
      #pragma unroll
      for (int ri = 0; ri < 8; ++ri) {
        const int q = w * 8 + ri;
        float s = 0.f;
        #pragma unroll
        for (int j = 0; j < 9; ++j) s += bf2f(s_p[q * PST + lane + 64 * j]);
        #pragma unroll
        for (int off = 1; off < 64; off <<= 1) s += __shfl_xor(s, off);
        if (lane == 0) s_denom[q] = s;
      }
    } else {
      // ---- top-32 + sparse gather: wave w owns rows w*8..w*8+7 ----
      for (int ri = 0; ri < 8; ++ri) {
        const int q = w * 8 + ri;
        unsigned key[9];
        #pragma unroll
        for (int j = 0; j < 9; ++j) {
          unsigned raw = s_p[q * PST + lane + 64 * j];
          key[j] = (raw & 0x8000u) ? (raw ^ 0xFFFFu) : (raw | 0x8000u);
        }
        unsigned prefix = 0;
        for (int bit = 15; bit >= 0; --bit) {
          const unsigned cand = prefix | (1u << bit);
          int cnt = 0;
          #pragma unroll
          for (int j = 0; j < 9; ++j)
            cnt += __popcll(__ballot(key[j] >= cand));
          if (cnt >= 32) prefix = cand;
          if (cnt == 32) break;
        }
        unsigned long long gtm[9], eqm[9];
        int cnt_gt = 0;
        #pragma unroll
        for (int j = 0; j < 9; ++j) {
          gtm[j] = __ballot(key[j] > prefix);
          eqm[j] = __ballot(key[j] == prefix);
          cnt_gt += __popcll(gtm[j]);
        }
        int run_gt = 0, run_eq = cnt_gt;
        float dsum = 0.f;
        #pragma unroll
        for (int j = 0; j < 9; ++j) {
          int slot = -1;
          if (key[j] > prefix) slot = run_gt + lanes_below(gtm[j]);
          else if (key[j] == prefix) {
            const int s2 = run_eq + lanes_below(eqm[j]);   // ties: lowest index
            if (s2 < 32) slot = s2;
          }
          if (slot >= 0) {
            const unsigned kk = key[j];
            const u16 raw = (kk & 0x8000u) ? (u16)(kk ^ 0x8000u) : (u16)(kk ^ 0xFFFFu);
            const float p = __expf(bf2f(raw));
            dsum += p;
            s_selp[q][slot] = p;
            s_seli[q][slot] = (u16)(c * 576 + lane + 64 * j);
          }
          run_gt += __popcll(gtm[j]);
          run_eq += __popcll(eqm[j]);
        }
        #pragma unroll
        for (int off = 1; off < 64; off <<= 1) dsum += __shfl_xor(dsum, off);
        if (lane == 0) s_denom[q] += dsum;
        // coalesced sparse PV gather: lane = dim d
        float ga = 0.f;
        const u16* vp = vbuf + (size_t)bh * 2880 * 64 + lane;
        #pragma unroll 8
        for (int i = 0; i < 32; ++i) {
          const float p = s_selp[q][i];
          const int keyi = s_seli[q][i];
          ga += p * bf2f(vp[(size_t)keyi * 64]);
        }
        s_O[q][lane] += ga;
      }
    }
    __syncthreads();
  }

  // ---- epilogue: wave w owns cols d = w*16..w*16+15 ----
  const int d = w * 16 + l15;
  #pragma unroll
  for (int qa = 0; qa < 2; ++qa)
    #pragma unroll
    for (int r = 0; r < 4; ++r) {
      const int row = qa * 16 + rg * 4 + r;
      const float val = (accO[qa][r] + s_O[row][d]) / s_denom[row];
      aout[((size_t)(b * 576 + q0 + row)) * 768 + h * 64 + d] = f2bf(val);
    }
}

// ---------------- host launcher ----------------
extern "C" void kernel_launch(void* const* d_in, const int* in_sizes, int n_in,
                              void* d_out, int out_size, void* d_ws, size_t ws_size,
                              hipStream_t stream)
{
  const float* x      = (const float*)d_in[0];
  const float* qkv_w  = (const float*)d_in[1];
  const float* proj_w = (const float*)d_in[2];
  const float* proj_b = (const float*)d_in[3];
  float* out = (float*)d_out;

  char* ws = (char*)d_ws;
  size_t off = 0;
  auto alloc = [&](size_t bytes) -> void* {
    void* p = ws + off;
    off += (bytes + 255) & ~(size_t)255;
    return p;
  };
  u16* xb   = (u16*)alloc((size_t)23040 * 768 * 2);   // x bf16
  u16* wqb  = (u16*)alloc((size_t)2304 * 768 * 2);    // qkv_w bf16
  u16* wpb  = (u16*)alloc((size_t)768 * 768 * 2);     // proj_w bf16
  u16* qbuf = (u16*)alloc((size_t)96 * 576 * 64 * 2); // q (pre-scaled 1/8)
  u16* vtb  = (u16*)alloc((size_t)96 * 64 * 576 * 2); // v^T, qa cols only
  u16* aout = (u16*)alloc((size_t)4608 * 768 * 2);    // attention output (B*hw, C)
  // k/v (70.8 MB) live inside d_out during the early phases; proj +
  // passthrough overwrite d_out only after attn has consumed them.
  u16* kbuf = (u16*)d_out;
  u16* vbuf = kbuf + (size_t)96 * 2880 * 64;

  cvt_kernel<<<17280, 256, 0, stream>>>(x, xb, 17694720 / 4);
  cvt_kernel<<<1728, 256, 0, stream>>>(qkv_w, wqb, 1769472 / 4);
  cvt_kernel<<<576, 256, 0, stream>>>(proj_w, wpb, 589824 / 4);
  gemm_nt<0><<<dim3(36, 360), 256, 0, stream>>>(xb, wqb, nullptr,
                                                qbuf, kbuf, vbuf, vtb, nullptr);
  attn_kernel<<<dim3(18, 12, 8), 256, 0, stream>>>(qbuf, kbuf, vbuf, vtb, aout);
  gemm_nt<1><<<dim3(12, 72), 256, 0, stream>>>(aout, wpb, proj_b,
                                               nullptr, nullptr, nullptr, nullptr, out);
  copy_tail_kernel<<<13824, 256, 0, stream>>>(x, out);
}

// Round 3
// 552.752 us; speedup vs baseline: 2.0966x; 1.3596x over previous
//
#include <hip/hip_runtime.h>
#include <hip/hip_bf16.h>

// Attention_89335319756981 — MI355X bf16-MFMA implementation, round 3.
// B=8, N=2880 (hw=576 + T=4 frames of 576), C=768, H=12, hd=64, TOPK=32.
//
// Round-3 change: attn uses 16 q-rows/block (LDS 26KB -> 6 blocks/CU,
// 24 waves/CU) + bijective XCD swizzle (one batch per XCD -> K fetched
// once per XCD instead of 8x).

using s16x8 = __attribute__((ext_vector_type(8))) short;
using f32x4 = __attribute__((ext_vector_type(4))) float;
typedef unsigned short u16;

#define MFMA_B16(A,B,C) __builtin_amdgcn_mfma_f32_16x16x32_bf16(A,B,C,0,0,0)

__device__ __forceinline__ u16 f2bf(float f) {
  unsigned u = __float_as_uint(f);
  u += 0x7FFFu + ((u >> 16) & 1u);          // RNE, no NaN inputs here
  return (u16)(u >> 16);
}
__device__ __forceinline__ float bf2f(u16 h) {
  return __uint_as_float(((unsigned)h) << 16);
}
__device__ __forceinline__ int lanes_below(unsigned long long m) {
  return __builtin_amdgcn_mbcnt_hi((unsigned)(m >> 32),
         __builtin_amdgcn_mbcnt_lo((unsigned)m, 0));
}

// ---------------- f32 -> bf16 convert (4 elems/thread) ----------------
__global__ __launch_bounds__(256) void cvt_kernel(const float* __restrict__ src,
                                                  u16* __restrict__ dst, int n4) {
  int i = blockIdx.x * blockDim.x + threadIdx.x;
  if (i >= n4) return;
  float4 v = ((const float4*)src)[i];
  unsigned lo = (unsigned)f2bf(v.x) | ((unsigned)f2bf(v.y) << 16);
  unsigned hi = (unsigned)f2bf(v.z) | ((unsigned)f2bf(v.w) << 16);
  uint2 o; o.x = lo; o.y = hi;
  ((uint2*)dst)[i] = o;
}

// ---------------- passthrough copy: out[:,576:,:] = x[:,576:,:] ----------------
__global__ __launch_bounds__(256) void copy_tail_kernel(const float* __restrict__ x,
                                                        float* __restrict__ out) {
  int i = blockIdx.x * blockDim.x + threadIdx.x;   // float4 units
  int b = i / 442368;                              // 2304*768/4 per batch
  int off = i - b * 442368;
  size_t e = (size_t)b * 552960 + 110592 + off;    // (b*2880+576)*768/4 + off
  ((float4*)out)[e] = ((const float4*)x)[e];
}

// ---------------- NT GEMM: C[m][n] = sum_k A[m][k]*Bw[n][k], bf16 MFMA ----------------
// 64x64 block tile, 4 waves of 32x32, K-step 64. LDS padded stride 144B.
// MODE 0: QKV epilogue (scatter q/k/v/vT-qa). MODE 1: proj epilogue (f32 + bias -> out).
template<int MODE>
__global__ __launch_bounds__(256) void gemm_nt(
    const u16* __restrict__ A, const u16* __restrict__ Bw,
    const float* __restrict__ bias,
    u16* __restrict__ qbuf, u16* __restrict__ kbuf,
    u16* __restrict__ vbuf, u16* __restrict__ vtb,
    float* __restrict__ fout)
{
  constexpr int LDT = 72;   // u16 per LDS row (144 B)
  __shared__ __align__(16) u16 sA[64 * LDT];
  __shared__ __align__(16) u16 sB[64 * LDT];
  const int n0 = blockIdx.x * 64;
  const int m0 = blockIdx.y * 64;
  if (MODE == 0) {
    // q columns (n<768) only need rows r<576 of each batch (m-tile%45 < 9)
    if (n0 < 768 && (blockIdx.y % 45) >= 9) return;
  }
  const int tid = threadIdx.x;
  const int w = tid >> 6, lane = tid & 63;
  const int srow = tid >> 2, scb = tid & 3;
  const int mh = (w >> 1) * 32, nh = (w & 1) * 32;
  f32x4 z = {0.f, 0.f, 0.f, 0.f};
  f32x4 acc[2][2] = {{z, z}, {z, z}};

  for (int k0 = 0; k0 < 768; k0 += 64) {
    __syncthreads();
    #pragma unroll
    for (int c = scb; c < 8; c += 4) {
      *(int4*)&sA[srow * LDT + c * 8] =
          *(const int4*)&A[(size_t)(m0 + srow) * 768 + k0 + c * 8];
      *(int4*)&sB[srow * LDT + c * 8] =
          *(const int4*)&Bw[(size_t)(n0 + srow) * 768 + k0 + c * 8];
    }
    __syncthreads();
    #pragma unroll
    for (int kk = 0; kk < 2; ++kk) {
      const int ko = kk * 32 + (lane >> 4) * 8;
      s16x8 a0 = *(const s16x8*)&sA[(mh +      (lane & 15)) * LDT + ko];
      s16x8 a1 = *(const s16x8*)&sA[(mh + 16 + (lane & 15)) * LDT + ko];
      s16x8 b0 = *(const s16x8*)&sB[(nh +      (lane & 15)) * LDT + ko];
      s16x8 b1 = *(const s16x8*)&sB[(nh + 16 + (lane & 15)) * LDT + ko];
      acc[0][0] = MFMA_B16(a0, b0, acc[0][0]);
      acc[0][1] = MFMA_B16(a0, b1, acc[0][1]);
      acc[1][0] = MFMA_B16(a1, b0, acc[1][0]);
      acc[1][1] = MFMA_B16(a1, b1, acc[1][1]);
    }
  }

  if (MODE == 0) {
    const int which = n0 / 768;           // uniform per block
    const int h = (n0 % 768) >> 6;        // head, uniform
    #pragma unroll
    for (int mi = 0; mi < 2; ++mi)
      #pragma unroll
      for (int ni = 0; ni < 2; ++ni)
        #pragma unroll
        for (int r = 0; r < 4; ++r) {
          const int gm = m0 + mh + mi * 16 + (lane >> 4) * 4 + r;
          const int d  = nh + ni * 16 + (lane & 15);
          const int b  = gm / 2880;
          const int rr = gm - b * 2880;
          const float c = acc[mi][ni][r];
          if (which == 0) {
            if (rr < 576)
              qbuf[((size_t)(b * 12 + h) * 576 + rr) * 64 + d] = f2bf(c * 0.125f);
          } else if (which == 1) {
            kbuf[((size_t)(b * 12 + h) * 2880 + rr) * 64 + d] = f2bf(c);
          } else {
            const u16 bv = f2bf(c);
            vbuf[((size_t)(b * 12 + h) * 2880 + rr) * 64 + d] = bv;
            if (rr < 576)  // vT only needed for the dense (qa) PV region
              vtb[((size_t)((b * 12 + h) * 64 + d)) * 576 + rr] = bv;
          }
        }
  } else {
    #pragma unroll
    for (int mi = 0; mi < 2; ++mi)
      #pragma unroll
      for (int ni = 0; ni < 2; ++ni)
        #pragma unroll
        for (int r = 0; r < 4; ++r) {
          const int gm = m0 + mh + mi * 16 + (lane >> 4) * 4 + r;
          const int gn = n0 + nh + ni * 16 + (lane & 15);
          const int b = gm / 576;
          const int q = gm - b * 576;
          fout[((size_t)b * 2880 + q) * 768 + gn] = acc[mi][ni][r] + bias[gn];
        }
  }
}

// ---------------- fused attention, round 3 ----------------
// block = (b, h, 16 q-rows), 256 threads (4 waves), ~26KB LDS -> 6 blocks/CU.
// Bijective XCD swizzle: each XCD owns one batch (K panels stay L2-local).
// 5 key-chunks of 576. Chunk 0 (qa): scores->exp->LDS P; dense PV MFMA into
// registers; denom. Chunks 1-4: scores->LDS; per-wave top-32 (ballot binary
// search) + denom add + coalesced sparse V gather into LDS s_O.
__global__ __launch_bounds__(256, 6) void attn_kernel(
    const u16* __restrict__ qbuf, const u16* __restrict__ kbuf,
    const u16* __restrict__ vbuf, const u16* __restrict__ vtb,
    u16* __restrict__ aout)
{
  constexpr int PST = 584;                       // u16 stride (1168 B, 16B aligned)
  __shared__ __align__(16) u16 s_p[16 * PST];    // 18.7 KB scores / P
  __shared__ float s_selp[16][32];               // exp(score) of selected
  __shared__ u16   s_seli[16][32];               // global key idx (576..2879)
  __shared__ float s_O[16][64];                  // sparse PV accumulator
  __shared__ float s_denom[16];

  // XCD-bijective remap: physical xcd = bid%8 -> logical L walks (qt,h) within
  // one batch per XCD. 3456 = 8 * 432, 432 = 36 qt * 12 h.
  const int bid = blockIdx.x;
  const int L = (bid & 7) * 432 + (bid >> 3);
  const int qt = L % 36;
  const int h  = (L / 36) % 12;
  const int b  = L / 432;
  const int bh = b * 12 + h;
  const int q0 = qt * 16;
  const int tid = threadIdx.x, w = tid >> 6, lane = tid & 63;
  const int l15 = lane & 15, rg = lane >> 4;
  const int ko = rg * 8;

  #pragma unroll
  for (int i = 0; i < 4; ++i) ((float*)s_O)[tid + 256 * i] = 0.f;

  // Q A-fragments for the block's 16 rows (2 K-halves)
  const u16* qp = qbuf + ((size_t)bh * 576 + q0) * 64;
  s16x8 aQ[2];
  aQ[0] = *(const s16x8*)&qp[l15 * 64 + ko];
  aQ[1] = *(const s16x8*)&qp[l15 * 64 + 32 + ko];

  const u16* kp = kbuf + (size_t)bh * 2880 * 64;
  f32x4 zz = {0.f, 0.f, 0.f, 0.f};
  f32x4 accO = zz;

  for (int c = 0; c < 5; ++c) {
    // ---- scores: wave w covers chunk-local keys [w*144, w*144+144) ----
    #pragma unroll 3
    for (int t = 0; t < 9; ++t) {
      const int wk = w * 144 + t * 16;
      const u16* kr = kp + (size_t)(c * 576 + wk + l15) * 64 + ko;
      s16x8 kf0 = *(const s16x8*)&kr[0];
      s16x8 kf1 = *(const s16x8*)&kr[32];
      f32x4 a0 = zz;
      a0 = MFMA_B16(aQ[0], kf0, a0);
      a0 = MFMA_B16(aQ[1], kf1, a0);
      if (c == 0) {
        #pragma unroll
        for (int r = 0; r < 4; ++r)
          s_p[(rg * 4 + r) * PST + wk + l15] = f2bf(__expf(a0[r]));
      } else {
        #pragma unroll
        for (int r = 0; r < 4; ++r)
          s_p[(rg * 4 + r) * PST + wk + l15] = f2bf(a0[r]);
      }
    }
    __syncthreads();

    if (c == 0) {
      // ---- dense PV over qa: wave w owns output cols d = w*16..w*16+15 ----
      const u16* vt = vtb + ((size_t)bh * 64 + w * 16 + l15) * 576;
      #pragma unroll 3
      for (int k0 = 0; k0 < 576; k0 += 32) {
        s16x8 vf = *(const s16x8*)&vt[k0 + ko];
        s16x8 pa = *(const s16x8*)&s_p[l15 * PST + k0 + ko];
        accO = MFMA_B16(pa, vf, accO);
      }
      // ---- denom over qa: wave w owns rows w*4..w*4+3 ----
      #pragma unroll
      for (int ri = 0; ri < 4; ++ri) {
        const int q = w * 4 + ri;
        float s = 0.f;
        #pragma unroll
        for (int j = 0; j < 9; ++j) s += bf2f(s_p[q * PST + lane + 64 * j]);
        #pragma unroll
        for (int off = 1; off < 64; off <<= 1) s += __shfl_xor(s, off);
        if (lane == 0) s_denom[q] = s;
      }
    } else {
      // ---- top-32 + sparse gather: wave w owns rows w*4..w*4+3 ----
      for (int ri = 0; ri < 4; ++ri) {
        const int q = w * 4 + ri;
        unsigned key[9];
        #pragma unroll
        for (int j = 0; j < 9; ++j) {
          unsigned raw = s_p[q * PST + lane + 64 * j];
          key[j] = (raw & 0x8000u) ? (raw ^ 0xFFFFu) : (raw | 0x8000u);
        }
        unsigned prefix = 0;
        for (int bit = 15; bit >= 0; --bit) {
          const unsigned cand = prefix | (1u << bit);
          int cnt = 0;
          #pragma unroll
          for (int j = 0; j < 9; ++j)
            cnt += __popcll(__ballot(key[j] >= cand));
          if (cnt >= 32) prefix = cand;
          if (cnt == 32) break;
        }
        unsigned long long gtm[9], eqm[9];
        int cnt_gt = 0;
        #pragma unroll
        for (int j = 0; j < 9; ++j) {
          gtm[j] = __ballot(key[j] > prefix);
          eqm[j] = __ballot(key[j] == prefix);
          cnt_gt += __popcll(gtm[j]);
        }
        int run_gt = 0, run_eq = cnt_gt;
        float dsum = 0.f;
        #pragma unroll
        for (int j = 0; j < 9; ++j) {
          int slot = -1;
          if (key[j] > prefix) slot = run_gt + lanes_below(gtm[j]);
          else if (key[j] == prefix) {
            const int s2 = run_eq + lanes_below(eqm[j]);   // ties: lowest index
            if (s2 < 32) slot = s2;
          }
          if (slot >= 0) {
            const unsigned kk = key[j];
            const u16 raw = (kk & 0x8000u) ? (u16)(kk ^ 0x8000u) : (u16)(kk ^ 0xFFFFu);
            const float p = __expf(bf2f(raw));
            dsum += p;
            s_selp[q][slot] = p;
            s_seli[q][slot] = (u16)(c * 576 + lane + 64 * j);
          }
          run_gt += __popcll(gtm[j]);
          run_eq += __popcll(eqm[j]);
        }
        #pragma unroll
        for (int off = 1; off < 64; off <<= 1) dsum += __shfl_xor(dsum, off);
        if (lane == 0) s_denom[q] += dsum;
        // coalesced sparse PV gather: lane = dim d
        float ga = 0.f;
        const u16* vp = vbuf + (size_t)bh * 2880 * 64 + lane;
        #pragma unroll 8
        for (int i = 0; i < 32; ++i) {
          const float p = s_selp[q][i];
          const int keyi = s_seli[q][i];
          ga += p * bf2f(vp[(size_t)keyi * 64]);
        }
        s_O[q][lane] += ga;
      }
    }
    __syncthreads();
  }

  // ---- epilogue: wave w owns cols d = w*16..w*16+15 ----
  const int d = w * 16 + l15;
  #pragma unroll
  for (int r = 0; r < 4; ++r) {
    const int row = rg * 4 + r;
    const float val = (accO[r] + s_O[row][d]) / s_denom[row];
    aout[((size_t)(b * 576 + q0 + row)) * 768 + h * 64 + d] = f2bf(val);
  }
}

// ---------------- host launcher ----------------
extern "C" void kernel_launch(void* const* d_in, const int* in_sizes, int n_in,
                              void* d_out, int out_size, void* d_ws, size_t ws_size,
                              hipStream_t stream)
{
  const float* x      = (const float*)d_in[0];
  const float* qkv_w  = (const float*)d_in[1];
  const float* proj_w = (const float*)d_in[2];
  const float* proj_b = (const float*)d_in[3];
  float* out = (float*)d_out;

  char* ws = (char*)d_ws;
  size_t off = 0;
  auto alloc = [&](size_t bytes) -> void* {
    void* p = ws + off;
    off += (bytes + 255) & ~(size_t)255;
    return p;
  };
  u16* xb   = (u16*)alloc((size_t)23040 * 768 * 2);   // x bf16
  u16* wqb  = (u16*)alloc((size_t)2304 * 768 * 2);    // qkv_w bf16
  u16* wpb  = (u16*)alloc((size_t)768 * 768 * 2);     // proj_w bf16
  u16* qbuf = (u16*)alloc((size_t)96 * 576 * 64 * 2); // q (pre-scaled 1/8)
  u16* vtb  = (u16*)alloc((size_t)96 * 64 * 576 * 2); // v^T, qa cols only
  u16* aout = (u16*)alloc((size_t)4608 * 768 * 2);    // attention output (B*hw, C)
  // k/v (70.8 MB) live inside d_out during the early phases; proj +
  // passthrough overwrite d_out only after attn has consumed them.
  u16* kbuf = (u16*)d_out;
  u16* vbuf = kbuf + (size_t)96 * 2880 * 64;

  cvt_kernel<<<17280, 256, 0, stream>>>(x, xb, 17694720 / 4);
  cvt_kernel<<<1728, 256, 0, stream>>>(qkv_w, wqb, 1769472 / 4);
  cvt_kernel<<<576, 256, 0, stream>>>(proj_w, wpb, 589824 / 4);
  gemm_nt<0><<<dim3(36, 360), 256, 0, stream>>>(xb, wqb, nullptr,
                                                qbuf, kbuf, vbuf, vtb, nullptr);
  attn_kernel<<<3456, 256, 0, stream>>>(qbuf, kbuf, vbuf, vtb, aout);
  gemm_nt<1><<<dim3(12, 72), 256, 0, stream>>>(aout, wpb, proj_b,
                                               nullptr, nullptr, nullptr, nullptr, out);
  copy_tail_kernel<<<13824, 256, 0, stream>>>(x, out);
}

// Round 4
// 533.763 us; speedup vs baseline: 2.1712x; 1.0356x over previous
//
#include <hip/hip_runtime.h>
#include <hip/hip_bf16.h>

// Attention_89335319756981 — MI355X bf16-MFMA implementation, round 4.
// B=8, N=2880 (hw=576 + T=4 frames of 576), C=768, H=12, hd=64, TOPK=32.
//
// Round-4 change: sparse PV gather replaced by selective exp-writeback into
// the score LDS (selected -> exp, others -> 0) + dense PV MFMA per chunk.
// LDS 26->19KB, 8 blocks/CU. vtb back to full 2880 keys.

using s16x8 = __attribute__((ext_vector_type(8))) short;
using f32x4 = __attribute__((ext_vector_type(4))) float;
typedef unsigned short u16;

#define MFMA_B16(A,B,C) __builtin_amdgcn_mfma_f32_16x16x32_bf16(A,B,C,0,0,0)

__device__ __forceinline__ u16 f2bf(float f) {
  unsigned u = __float_as_uint(f);
  u += 0x7FFFu + ((u >> 16) & 1u);          // RNE, no NaN inputs here
  return (u16)(u >> 16);
}
__device__ __forceinline__ float bf2f(u16 h) {
  return __uint_as_float(((unsigned)h) << 16);
}
__device__ __forceinline__ int lanes_below(unsigned long long m) {
  return __builtin_amdgcn_mbcnt_hi((unsigned)(m >> 32),
         __builtin_amdgcn_mbcnt_lo((unsigned)m, 0));
}

// ---------------- f32 -> bf16 convert (4 elems/thread) ----------------
__global__ __launch_bounds__(256) void cvt_kernel(const float* __restrict__ src,
                                                  u16* __restrict__ dst, int n4) {
  int i = blockIdx.x * blockDim.x + threadIdx.x;
  if (i >= n4) return;
  float4 v = ((const float4*)src)[i];
  unsigned lo = (unsigned)f2bf(v.x) | ((unsigned)f2bf(v.y) << 16);
  unsigned hi = (unsigned)f2bf(v.z) | ((unsigned)f2bf(v.w) << 16);
  uint2 o; o.x = lo; o.y = hi;
  ((uint2*)dst)[i] = o;
}

// ---------------- passthrough copy: out[:,576:,:] = x[:,576:,:] ----------------
__global__ __launch_bounds__(256) void copy_tail_kernel(const float* __restrict__ x,
                                                        float* __restrict__ out) {
  int i = blockIdx.x * blockDim.x + threadIdx.x;   // float4 units
  int b = i / 442368;                              // 2304*768/4 per batch
  int off = i - b * 442368;
  size_t e = (size_t)b * 552960 + 110592 + off;    // (b*2880+576)*768/4 + off
  ((float4*)out)[e] = ((const float4*)x)[e];
}

// ---------------- NT GEMM: C[m][n] = sum_k A[m][k]*Bw[n][k], bf16 MFMA ----------------
// 64x64 block tile, 4 waves of 32x32, K-step 64. LDS padded stride 144B.
// MODE 0: QKV epilogue (scatter q/k/v/vT). MODE 1: proj epilogue (f32 + bias -> out).
template<int MODE>
__global__ __launch_bounds__(256) void gemm_nt(
    const u16* __restrict__ A, const u16* __restrict__ Bw,
    const float* __restrict__ bias,
    u16* __restrict__ qbuf, u16* __restrict__ kbuf,
    u16* __restrict__ vbuf, u16* __restrict__ vtb,
    float* __restrict__ fout)
{
  constexpr int LDT = 72;   // u16 per LDS row (144 B)
  __shared__ __align__(16) u16 sA[64 * LDT];
  __shared__ __align__(16) u16 sB[64 * LDT];
  const int n0 = blockIdx.x * 64;
  const int m0 = blockIdx.y * 64;
  if (MODE == 0) {
    // q columns (n<768) only need rows r<576 of each batch (m-tile%45 < 9)
    if (n0 < 768 && (blockIdx.y % 45) >= 9) return;
  }
  const int tid = threadIdx.x;
  const int w = tid >> 6, lane = tid & 63;
  const int srow = tid >> 2, scb = tid & 3;
  const int mh = (w >> 1) * 32, nh = (w & 1) * 32;
  f32x4 z = {0.f, 0.f, 0.f, 0.f};
  f32x4 acc[2][2] = {{z, z}, {z, z}};

  for (int k0 = 0; k0 < 768; k0 += 64) {
    __syncthreads();
    #pragma unroll
    for (int c = scb; c < 8; c += 4) {
      *(int4*)&sA[srow * LDT + c * 8] =
          *(const int4*)&A[(size_t)(m0 + srow) * 768 + k0 + c * 8];
      *(int4*)&sB[srow * LDT + c * 8] =
          *(const int4*)&Bw[(size_t)(n0 + srow) * 768 + k0 + c * 8];
    }
    __syncthreads();
    #pragma unroll
    for (int kk = 0; kk < 2; ++kk) {
      const int ko = kk * 32 + (lane >> 4) * 8;
      s16x8 a0 = *(const s16x8*)&sA[(mh +      (lane & 15)) * LDT + ko];
      s16x8 a1 = *(const s16x8*)&sA[(mh + 16 + (lane & 15)) * LDT + ko];
      s16x8 b0 = *(const s16x8*)&sB[(nh +      (lane & 15)) * LDT + ko];
      s16x8 b1 = *(const s16x8*)&sB[(nh + 16 + (lane & 15)) * LDT + ko];
      acc[0][0] = MFMA_B16(a0, b0, acc[0][0]);
      acc[0][1] = MFMA_B16(a0, b1, acc[0][1]);
      acc[1][0] = MFMA_B16(a1, b0, acc[1][0]);
      acc[1][1] = MFMA_B16(a1, b1, acc[1][1]);
    }
  }

  if (MODE == 0) {
    const int which = n0 / 768;           // uniform per block
    const int h = (n0 % 768) >> 6;        // head, uniform
    #pragma unroll
    for (int mi = 0; mi < 2; ++mi)
      #pragma unroll
      for (int ni = 0; ni < 2; ++ni)
        #pragma unroll
        for (int r = 0; r < 4; ++r) {
          const int gm = m0 + mh + mi * 16 + (lane >> 4) * 4 + r;
          const int d  = nh + ni * 16 + (lane & 15);
          const int b  = gm / 2880;
          const int rr = gm - b * 2880;
          const float c = acc[mi][ni][r];
          if (which == 0) {
            if (rr < 576)
              qbuf[((size_t)(b * 12 + h) * 576 + rr) * 64 + d] = f2bf(c * 0.125f);
          } else if (which == 1) {
            kbuf[((size_t)(b * 12 + h) * 2880 + rr) * 64 + d] = f2bf(c);
          } else {
            const u16 bv = f2bf(c);
            vbuf[((size_t)(b * 12 + h) * 2880 + rr) * 64 + d] = bv;
            vtb[((size_t)((b * 12 + h) * 64 + d)) * 2880 + rr] = bv;
          }
        }
  } else {
    #pragma unroll
    for (int mi = 0; mi < 2; ++mi)
      #pragma unroll
      for (int ni = 0; ni < 2; ++ni)
        #pragma unroll
        for (int r = 0; r < 4; ++r) {
          const int gm = m0 + mh + mi * 16 + (lane >> 4) * 4 + r;
          const int gn = n0 + nh + ni * 16 + (lane & 15);
          const int b = gm / 576;
          const int q = gm - b * 576;
          fout[((size_t)b * 2880 + q) * 768 + gn] = acc[mi][ni][r] + bias[gn];
        }
  }
}

// ---------------- fused attention, round 4 ----------------
// block = (b, h, 16 q-rows), 256 threads (4 waves), ~19KB LDS -> 8 blocks/CU.
// Bijective XCD swizzle (one batch per XCD). 5 key-chunks of 576.
// Per chunk: scores -> LDS; (c==0: exp directly + denom) (c>0: per-wave exact
// top-32 via ballot binary search, then selective exp-writeback: selected ->
// exp(score), others -> 0); dense PV MFMA per chunk accumulates in registers.
__global__ __launch_bounds__(256, 8) void attn_kernel(
    const u16* __restrict__ qbuf, const u16* __restrict__ kbuf,
    const u16* __restrict__ vbuf, const u16* __restrict__ vtb,
    u16* __restrict__ aout)
{
  constexpr int PST = 584;                       // u16 stride (1168 B, 16B aligned)
  __shared__ __align__(16) u16 s_p[16 * PST];    // 18.7 KB scores / P
  __shared__ float s_denom[16];

  // XCD-bijective remap: 3456 = 8 XCDs * 432; 432 = 36 qt * 12 h (one batch/XCD)
  const int bid = blockIdx.x;
  const int L = (bid & 7) * 432 + (bid >> 3);
  const int qt = L % 36;
  const int h  = (L / 36) % 12;
  const int b  = L / 432;
  const int bh = b * 12 + h;
  const int q0 = qt * 16;
  const int tid = threadIdx.x, w = tid >> 6, lane = tid & 63;
  const int l15 = lane & 15, rg = lane >> 4;
  const int ko = rg * 8;

  // Q A-fragments for the block's 16 rows (2 K-halves)
  const u16* qp = qbuf + ((size_t)bh * 576 + q0) * 64;
  s16x8 aQ[2];
  aQ[0] = *(const s16x8*)&qp[l15 * 64 + ko];
  aQ[1] = *(const s16x8*)&qp[l15 * 64 + 32 + ko];

  const u16* kp = kbuf + (size_t)bh * 2880 * 64;
  const u16* vt = vtb + ((size_t)bh * 64 + w * 16 + l15) * 2880;
  f32x4 zz = {0.f, 0.f, 0.f, 0.f};
  f32x4 accO = zz;

  for (int c = 0; c < 5; ++c) {
    // ---- scores: wave w covers chunk-local keys [w*144, w*144+144) ----
    #pragma unroll 3
    for (int t = 0; t < 9; ++t) {
      const int wk = w * 144 + t * 16;
      const u16* kr = kp + (size_t)(c * 576 + wk + l15) * 64 + ko;
      s16x8 kf0 = *(const s16x8*)&kr[0];
      s16x8 kf1 = *(const s16x8*)&kr[32];
      f32x4 a0 = zz;
      a0 = MFMA_B16(aQ[0], kf0, a0);
      a0 = MFMA_B16(aQ[1], kf1, a0);
      if (c == 0) {
        #pragma unroll
        for (int r = 0; r < 4; ++r)
          s_p[(rg * 4 + r) * PST + wk + l15] = f2bf(__expf(a0[r]));
      } else {
        #pragma unroll
        for (int r = 0; r < 4; ++r)
          s_p[(rg * 4 + r) * PST + wk + l15] = f2bf(a0[r]);
      }
    }
    __syncthreads();

    if (c == 0) {
      // ---- denom over qa: wave w owns rows w*4..w*4+3 ----
      #pragma unroll
      for (int ri = 0; ri < 4; ++ri) {
        const int q = w * 4 + ri;
        float s = 0.f;
        #pragma unroll
        for (int j = 0; j < 9; ++j) s += bf2f(s_p[q * PST + lane + 64 * j]);
        #pragma unroll
        for (int off = 1; off < 64; off <<= 1) s += __shfl_xor(s, off);
        if (lane == 0) s_denom[q] = s;
      }
    } else {
      // ---- top-32 + selective exp-writeback: wave w owns rows w*4..w*4+3 ----
      for (int ri = 0; ri < 4; ++ri) {
        const int q = w * 4 + ri;
        unsigned key[9];
        #pragma unroll
        for (int j = 0; j < 9; ++j) {
          unsigned raw = s_p[q * PST + lane + 64 * j];
          key[j] = (raw & 0x8000u) ? (raw ^ 0xFFFFu) : (raw | 0x8000u);
        }
        unsigned prefix = 0;
        for (int bit = 15; bit >= 0; --bit) {
          const unsigned cand = prefix | (1u << bit);
          int cnt = 0;
          #pragma unroll
          for (int j = 0; j < 9; ++j)
            cnt += __popcll(__ballot(key[j] >= cand));
          if (cnt >= 32) prefix = cand;
          if (cnt == 32) break;
        }
        unsigned long long eqm[9];
        int cnt_gt = 0;
        #pragma unroll
        for (int j = 0; j < 9; ++j) {
          cnt_gt += __popcll(__ballot(key[j] > prefix));
          eqm[j] = __ballot(key[j] == prefix);
        }
        const int rem = 32 - cnt_gt;     // #slots left for ties (lowest index wins)
        int run_eq = 0;
        float dsum = 0.f;
        #pragma unroll
        for (int j = 0; j < 9; ++j) {
          const unsigned kk = key[j];
          const bool sel = (kk > prefix) ||
              (kk == prefix && run_eq + lanes_below(eqm[j]) < rem);
          const u16 raw = (kk & 0x8000u) ? (u16)(kk ^ 0x8000u) : (u16)(kk ^ 0xFFFFu);
          const float e = __expf(bf2f(raw));
          const float p = sel ? e : 0.f;
          dsum += p;
          s_p[q * PST + lane + 64 * j] = f2bf(p);
          run_eq += __popcll(eqm[j]);
        }
        #pragma unroll
        for (int off = 1; off < 64; off <<= 1) dsum += __shfl_xor(dsum, off);
        if (lane == 0) s_denom[q] += dsum;
      }
      __syncthreads();   // P writeback visible before PV reads all rows
    }

    // ---- dense PV over this chunk: wave w owns output cols d = w*16..w*16+15 ----
    #pragma unroll 3
    for (int k0 = 0; k0 < 576; k0 += 32) {
      s16x8 vf = *(const s16x8*)&vt[c * 576 + k0 + ko];
      s16x8 pa = *(const s16x8*)&s_p[l15 * PST + k0 + ko];
      accO = MFMA_B16(pa, vf, accO);
    }
    __syncthreads();     // PV done before next chunk overwrites s_p
  }

  // ---- epilogue: wave w owns cols d = w*16..w*16+15 ----
  const int d = w * 16 + l15;
  #pragma unroll
  for (int r = 0; r < 4; ++r) {
    const int row = rg * 4 + r;
    const float val = accO[r] / s_denom[row];
    aout[((size_t)(b * 576 + q0 + row)) * 768 + h * 64 + d] = f2bf(val);
  }
}

// ---------------- host launcher ----------------
extern "C" void kernel_launch(void* const* d_in, const int* in_sizes, int n_in,
                              void* d_out, int out_size, void* d_ws, size_t ws_size,
                              hipStream_t stream)
{
  const float* x      = (const float*)d_in[0];
  const float* qkv_w  = (const float*)d_in[1];
  const float* proj_w = (const float*)d_in[2];
  const float* proj_b = (const float*)d_in[3];
  float* out = (float*)d_out;

  char* ws = (char*)d_ws;
  size_t off = 0;
  auto alloc = [&](size_t bytes) -> void* {
    void* p = ws + off;
    off += (bytes + 255) & ~(size_t)255;
    return p;
  };
  u16* xb   = (u16*)alloc((size_t)23040 * 768 * 2);   // x bf16
  u16* wqb  = (u16*)alloc((size_t)2304 * 768 * 2);    // qkv_w bf16
  u16* wpb  = (u16*)alloc((size_t)768 * 768 * 2);     // proj_w bf16
  u16* qbuf = (u16*)alloc((size_t)96 * 576 * 64 * 2); // q (pre-scaled 1/8)
  u16* vtb  = (u16*)alloc((size_t)96 * 64 * 2880 * 2);// v^T, full 2880 keys
  u16* aout = (u16*)alloc((size_t)4608 * 768 * 2);    // attention output (B*hw, C)
  // k/v (70.8 MB) live inside d_out during the early phases; proj +
  // passthrough overwrite d_out only after attn has consumed them.
  u16* kbuf = (u16*)d_out;
  u16* vbuf = kbuf + (size_t)96 * 2880 * 64;

  cvt_kernel<<<17280, 256, 0, stream>>>(x, xb, 17694720 / 4);
  cvt_kernel<<<1728, 256, 0, stream>>>(qkv_w, wqb, 1769472 / 4);
  cvt_kernel<<<576, 256, 0, stream>>>(proj_w, wpb, 589824 / 4);
  gemm_nt<0><<<dim3(36, 360), 256, 0, stream>>>(xb, wqb, nullptr,
                                                qbuf, kbuf, vbuf, vtb, nullptr);
  attn_kernel<<<3456, 256, 0, stream>>>(qbuf, kbuf, vbuf, vtb, aout);
  gemm_nt<1><<<dim3(12, 72), 256, 0, stream>>>(aout, wpb, proj_b,
                                               nullptr, nullptr, nullptr, nullptr, out);
  copy_tail_kernel<<<13824, 256, 0, stream>>>(x, out);
}